// Round 3
// baseline (107.485 us; speedup 1.0000x reference)
//
#include <hip/hip_runtime.h>
#include <math.h>

// B=1024, D=128, H=128
#define Bn 1024
#define Dn 128
#define Hn 128

// Single fused kernel: 256 blocks x 1024 threads (16 waves/CU, 1 block/CU).
// v4 = v1 backbone (quadratic phase 1, proven) + tail restructure:
//  - xs staged from xi registers pre-loop; wt_s pre-staged (no global reload)
//  - in-register shfl_xor(32) folds group pairs -> red is 32 KB (was 64)
//  - 4 barriers (was 5); tau runs concurrently with group-reduce;
//    Wr.x runs concurrently with Wd-matvec; LN sums split ysq+ysc.
__global__ __launch_bounds__(1024) void fused_resd1(
    const float* __restrict__ x,
    const float* __restrict__ Wd, const float* __restrict__ bd,
    const float* __restrict__ Wt, const float* __restrict__ bt,
    const float* __restrict__ Wa, const float* __restrict__ ba,
    const float* __restrict__ Wr, const float* __restrict__ br,
    const float* __restrict__ gamma, const float* __restrict__ beta,
    float* __restrict__ out) {
  const int t = threadIdx.x;
  const int c = t & 31;   // column quad: cols 4c..4c+3
  const int g = t >> 5;   // j-group in [0,32)
  const int i0 = blockIdx.x << 2;

  __shared__ float red[16][4][Dn];  // 32 KB: per-wave-pair partial column sums
  __shared__ float xs[4][Dn];
  __shared__ float dms[4][Dn];
  __shared__ float ms[4][Hn];
  __shared__ float ysq[4][Hn];      // relu(Wa.m + ba)
  __shared__ float ysc[4][Hn];      // Wr.x + br
  __shared__ float wt_s[Dn];
  __shared__ float tau_s[4];        // 1/tau

  // ---- Phase 1: all-pairs partial sums, 8 loads in flight ----
  float4 xi[4];
#pragma unroll
  for (int r = 0; r < 4; ++r)
    xi[r] = *(const float4*)(x + (size_t)(i0 + r) * Dn + c * 4);

  // Stage xs from registers (threads t<128 hold every row's quad c) and wt_s.
  if (g < 4) *(float4*)&xs[g][c * 4] = xi[g];
  if (t >= 128 && t < 256) wt_s[t - 128] = Wt[t - 128];

  float4 acc[4];
#pragma unroll
  for (int r = 0; r < 4; ++r) acc[r] = make_float4(0.f, 0.f, 0.f, 0.f);

  const float4* xq = (const float4*)x + (size_t)g * 32 * (Dn / 4) + c;
#pragma unroll 1
  for (int jj = 0; jj < 32; jj += 8) {
    float4 xj[8];
#pragma unroll
    for (int u = 0; u < 8; ++u) xj[u] = xq[(size_t)(jj + u) * (Dn / 4)];
#pragma unroll
    for (int u = 0; u < 8; ++u) {
#pragma unroll
      for (int r = 0; r < 4; ++r) {
        acc[r].x += fabsf(xi[r].x - xj[u].x);
        acc[r].y += fabsf(xi[r].y - xj[u].y);
        acc[r].z += fabsf(xi[r].z - xj[u].z);
        acc[r].w += fabsf(xi[r].w - xj[u].w);
      }
    }
  }

  // Fold the wave's two j-groups (g=2w, 2w+1) in-register, then half-wave
  // stores 32 KB of partials (16 group-pairs).
#pragma unroll
  for (int r = 0; r < 4; ++r) {
    acc[r].x += __shfl_xor(acc[r].x, 32, 64);
    acc[r].y += __shfl_xor(acc[r].y, 32, 64);
    acc[r].z += __shfl_xor(acc[r].z, 32, 64);
    acc[r].w += __shfl_xor(acc[r].w, 32, 64);
  }
  if ((t & 32) == 0) {
    const int w = g >> 1;
#pragma unroll
    for (int r = 0; r < 4; ++r) *(float4*)&red[w][r][c * 4] = acc[r];
  }
  __syncthreads();  // B1

  // ---- Window 1: group-reduce (t<512) concurrent with tau (512<=t<768) ----
  if (t < 512) {
    const int r = t >> 7, d = t & 127;
    float s = 0.f;
#pragma unroll
    for (int gg = 0; gg < 16; ++gg) s += red[gg][r][d];
    dms[r][d] = s * (1.0f / 1024.0f);
  } else if (t < 768) {
    const int tt = t - 512;
    const int r = tt >> 6, p = tt & 63;
    float partial = xs[r][p] * wt_s[p] + xs[r][p + 64] * wt_s[p + 64];
#pragma unroll
    for (int off = 32; off; off >>= 1) partial += __shfl_xor(partial, off, 64);
    if (p == 0) {
      const float z = partial + bt[0];
      const float sp = fmaxf(z, 0.f) + log1pf(expf(-fabsf(z)));  // softplus
      tau_s[r] = 1.0f / (fmaxf(sp, 0.01f) + 1.0f);
    }
  }
  __syncthreads();  // B2

  // ---- Window 2: ms = (Wd.dm + bd)/tau (t<512) || ysc = Wr.x + br (t>=512) --
  if (t < 512) {
    const int r = t >> 7, h = t & 127;
    float m = bd[h];
    const float4* w = (const float4*)(Wd + (size_t)h * Dn);
#pragma unroll 4
    for (int k4 = 0; k4 < Dn / 4; ++k4) {
      const float4 wv = w[k4];
      const int k = k4 * 4;
      m += wv.x * dms[r][k] + wv.y * dms[r][k + 1] + wv.z * dms[r][k + 2] +
           wv.w * dms[r][k + 3];
    }
    ms[r][h] = m * tau_s[r];
  } else {
    const int tt = t - 512;
    const int r = tt >> 7, h = tt & 127;
    float cc = br[h];
    const float4* w = (const float4*)(Wr + (size_t)h * Dn);
#pragma unroll 4
    for (int k4 = 0; k4 < Dn / 4; ++k4) {
      const float4 wv = w[k4];
      const int k = k4 * 4;
      cc += wv.x * xs[r][k] + wv.y * xs[r][k + 1] + wv.z * xs[r][k + 2] +
            wv.w * xs[r][k + 3];
    }
    ysc[r][h] = cc;
  }
  __syncthreads();  // B3

  // ---- Window 3: ysq = relu(Wa.m + ba) (t<512) ----
  if (t < 512) {
    const int r = t >> 7, h = t & 127;
    float q = ba[h];
    const float4* w = (const float4*)(Wa + (size_t)h * Dn);
#pragma unroll 4
    for (int k4 = 0; k4 < Dn / 4; ++k4) {
      const float4 wv = w[k4];
      const int k = k4 * 4;
      q += wv.x * ms[r][k] + wv.y * ms[r][k + 1] + wv.z * ms[r][k + 2] +
           wv.w * ms[r][k + 3];
    }
    ysq[r][h] = fmaxf(q, 0.f);
  }
  __syncthreads();  // B4

  // ---- Phase 5: LayerNorm (one wave per row, t<256) ----
  if (t < 256) {
    const int r = t >> 6, p = t & 63;
    const float v0 = ysq[r][p] + ysc[r][p];
    const float v1 = ysq[r][p + 64] + ysc[r][p + 64];
    float s = v0 + v1;
    float q = v0 * v0 + v1 * v1;
#pragma unroll
    for (int off = 32; off; off >>= 1) {
      s += __shfl_xor(s, off, 64);
      q += __shfl_xor(q, off, 64);
    }
    const float mu = s * (1.0f / 128.0f);
    const float var = q * (1.0f / 128.0f) - mu * mu;
    const float rs = rsqrtf(var + 1e-5f);
    float* o = out + (size_t)(i0 + r) * Hn;
    o[p]      = (v0 - mu) * rs * gamma[p]      + beta[p];
    o[p + 64] = (v1 - mu) * rs * gamma[p + 64] + beta[p + 64];
  }
}

extern "C" void kernel_launch(void* const* d_in, const int* in_sizes, int n_in,
                              void* d_out, int out_size, void* d_ws,
                              size_t ws_size, hipStream_t stream) {
  const float* x     = (const float*)d_in[0];
  const float* Wd    = (const float*)d_in[1];
  const float* bd    = (const float*)d_in[2];
  const float* Wt    = (const float*)d_in[3];
  const float* bt    = (const float*)d_in[4];
  const float* Wa    = (const float*)d_in[5];
  const float* ba    = (const float*)d_in[6];
  const float* Wr    = (const float*)d_in[7];
  const float* br    = (const float*)d_in[8];
  const float* gamma = (const float*)d_in[9];
  const float* beta  = (const float*)d_in[10];
  float* out = (float*)d_out;

  fused_resd1<<<Bn / 4, 1024, 0, stream>>>(x, Wd, bd, Wt, bt, Wa, ba, Wr, br,
                                           gamma, beta, out);
  (void)in_sizes; (void)n_in; (void)out_size; (void)d_ws; (void)ws_size;
}

// Round 4
// 105.472 us; speedup vs baseline: 1.0191x; 1.0191x over previous
//
#include <hip/hip_runtime.h>
#include <math.h>

// B=1024, D=128, H=128
#define Bn 1024
#define Dn 128
#define Hn 128

// Single fused kernel: 256 blocks x 1024 threads (16 waves/CU, 1 block/CU).
// v5 = v4 structure with the scratch-spill bug fixed:
//   v4 staged xs via xi[g] (runtime-indexed register array -> compiler pushed
//   xi to scratch; VGPR=36, WRITE_SIZE=16.9MB, kernel 41us). v5 stages xs from
//   the g==0 threads with a STATIC #pragma unroll over r, keeping xi/acc/xj in
//   VGPRs.
// Tail (unchanged from v4): 4 barriers; tau runs concurrently with the
// group-reduce; Wr.x runs concurrently with the Wd-matvec; LN sums ysq+ysc.
__global__ __launch_bounds__(1024) void fused_resd1(
    const float* __restrict__ x,
    const float* __restrict__ Wd, const float* __restrict__ bd,
    const float* __restrict__ Wt, const float* __restrict__ bt,
    const float* __restrict__ Wa, const float* __restrict__ ba,
    const float* __restrict__ Wr, const float* __restrict__ br,
    const float* __restrict__ gamma, const float* __restrict__ beta,
    float* __restrict__ out) {
  const int t = threadIdx.x;
  const int c = t & 31;   // column quad: cols 4c..4c+3
  const int g = t >> 5;   // j-group in [0,32)
  const int i0 = blockIdx.x << 2;

  __shared__ float red[16][4][Dn];  // 32 KB: per-wave-pair partial column sums
  __shared__ float xs[4][Dn];
  __shared__ float dms[4][Dn];
  __shared__ float ms[4][Hn];
  __shared__ float ysq[4][Hn];      // relu(Wa.m + ba)
  __shared__ float ysc[4][Hn];      // Wr.x + br
  __shared__ float wt_s[Dn];
  __shared__ float tau_s[4];        // 1/tau

  // ---- Phase 1: all-pairs partial sums, 8 loads in flight ----
  float4 xi[4];
#pragma unroll
  for (int r = 0; r < 4; ++r)
    xi[r] = *(const float4*)(x + (size_t)(i0 + r) * Dn + c * 4);

  // Stage xs from registers: g==0 threads (c spans all 32 quads) write all 4
  // rows with STATIC r indices (no runtime register indexing -> no scratch).
  if (g == 0) {
#pragma unroll
    for (int r = 0; r < 4; ++r) *(float4*)&xs[r][c * 4] = xi[r];
  }
  if (t >= 128 && t < 256) wt_s[t - 128] = Wt[t - 128];

  float4 acc[4];
#pragma unroll
  for (int r = 0; r < 4; ++r) acc[r] = make_float4(0.f, 0.f, 0.f, 0.f);

  const float4* xq = (const float4*)x + (size_t)g * 32 * (Dn / 4) + c;
#pragma unroll 1
  for (int jj = 0; jj < 32; jj += 8) {
    float4 xj[8];
#pragma unroll
    for (int u = 0; u < 8; ++u) xj[u] = xq[(size_t)(jj + u) * (Dn / 4)];
#pragma unroll
    for (int u = 0; u < 8; ++u) {
#pragma unroll
      for (int r = 0; r < 4; ++r) {
        acc[r].x += fabsf(xi[r].x - xj[u].x);
        acc[r].y += fabsf(xi[r].y - xj[u].y);
        acc[r].z += fabsf(xi[r].z - xj[u].z);
        acc[r].w += fabsf(xi[r].w - xj[u].w);
      }
    }
  }

  // Fold the wave's two j-groups (g=2w, 2w+1) in-register; half-wave stores
  // 32 KB of partials (16 group-pairs).
#pragma unroll
  for (int r = 0; r < 4; ++r) {
    acc[r].x += __shfl_xor(acc[r].x, 32, 64);
    acc[r].y += __shfl_xor(acc[r].y, 32, 64);
    acc[r].z += __shfl_xor(acc[r].z, 32, 64);
    acc[r].w += __shfl_xor(acc[r].w, 32, 64);
  }
  if ((t & 32) == 0) {
    const int w = g >> 1;
#pragma unroll
    for (int r = 0; r < 4; ++r) *(float4*)&red[w][r][c * 4] = acc[r];
  }
  __syncthreads();  // B1

  // ---- Window 1: group-reduce (t<512) concurrent with tau (512<=t<768) ----
  if (t < 512) {
    const int r = t >> 7, d = t & 127;
    float s = 0.f;
#pragma unroll
    for (int gg = 0; gg < 16; ++gg) s += red[gg][r][d];
    dms[r][d] = s * (1.0f / 1024.0f);
  } else if (t < 768) {
    const int tt = t - 512;
    const int r = tt >> 6, p = tt & 63;
    float partial = xs[r][p] * wt_s[p] + xs[r][p + 64] * wt_s[p + 64];
#pragma unroll
    for (int off = 32; off; off >>= 1) partial += __shfl_xor(partial, off, 64);
    if (p == 0) {
      const float z = partial + bt[0];
      const float sp = fmaxf(z, 0.f) + log1pf(expf(-fabsf(z)));  // softplus
      tau_s[r] = 1.0f / (fmaxf(sp, 0.01f) + 1.0f);
    }
  }
  __syncthreads();  // B2

  // ---- Window 2: ms = (Wd.dm + bd)/tau (t<512) || ysc = Wr.x + br (t>=512) --
  if (t < 512) {
    const int r = t >> 7, h = t & 127;
    float m = bd[h];
    const float4* w = (const float4*)(Wd + (size_t)h * Dn);
#pragma unroll 4
    for (int k4 = 0; k4 < Dn / 4; ++k4) {
      const float4 wv = w[k4];
      const int k = k4 * 4;
      m += wv.x * dms[r][k] + wv.y * dms[r][k + 1] + wv.z * dms[r][k + 2] +
           wv.w * dms[r][k + 3];
    }
    ms[r][h] = m * tau_s[r];
  } else {
    const int tt = t - 512;
    const int r = tt >> 7, h = tt & 127;
    float cc = br[h];
    const float4* w = (const float4*)(Wr + (size_t)h * Dn);
#pragma unroll 4
    for (int k4 = 0; k4 < Dn / 4; ++k4) {
      const float4 wv = w[k4];
      const int k = k4 * 4;
      cc += wv.x * xs[r][k] + wv.y * xs[r][k + 1] + wv.z * xs[r][k + 2] +
            wv.w * xs[r][k + 3];
    }
    ysc[r][h] = cc;
  }
  __syncthreads();  // B3

  // ---- Window 3: ysq = relu(Wa.m + ba) (t<512) ----
  if (t < 512) {
    const int r = t >> 7, h = t & 127;
    float q = ba[h];
    const float4* w = (const float4*)(Wa + (size_t)h * Dn);
#pragma unroll 4
    for (int k4 = 0; k4 < Dn / 4; ++k4) {
      const float4 wv = w[k4];
      const int k = k4 * 4;
      q += wv.x * ms[r][k] + wv.y * ms[r][k + 1] + wv.z * ms[r][k + 2] +
           wv.w * ms[r][k + 3];
    }
    ysq[r][h] = fmaxf(q, 0.f);
  }
  __syncthreads();  // B4

  // ---- Phase 5: LayerNorm (one wave per row, t<256) ----
  if (t < 256) {
    const int r = t >> 6, p = t & 63;
    const float v0 = ysq[r][p] + ysc[r][p];
    const float v1 = ysq[r][p + 64] + ysc[r][p + 64];
    float s = v0 + v1;
    float q = v0 * v0 + v1 * v1;
#pragma unroll
    for (int off = 32; off; off >>= 1) {
      s += __shfl_xor(s, off, 64);
      q += __shfl_xor(q, off, 64);
    }
    const float mu = s * (1.0f / 128.0f);
    const float var = q * (1.0f / 128.0f) - mu * mu;
    const float rs = rsqrtf(var + 1e-5f);
    float* o = out + (size_t)(i0 + r) * Hn;
    o[p]      = (v0 - mu) * rs * gamma[p]      + beta[p];
    o[p + 64] = (v1 - mu) * rs * gamma[p + 64] + beta[p + 64];
  }
}

extern "C" void kernel_launch(void* const* d_in, const int* in_sizes, int n_in,
                              void* d_out, int out_size, void* d_ws,
                              size_t ws_size, hipStream_t stream) {
  const float* x     = (const float*)d_in[0];
  const float* Wd    = (const float*)d_in[1];
  const float* bd    = (const float*)d_in[2];
  const float* Wt    = (const float*)d_in[3];
  const float* bt    = (const float*)d_in[4];
  const float* Wa    = (const float*)d_in[5];
  const float* ba    = (const float*)d_in[6];
  const float* Wr    = (const float*)d_in[7];
  const float* br    = (const float*)d_in[8];
  const float* gamma = (const float*)d_in[9];
  const float* beta  = (const float*)d_in[10];
  float* out = (float*)d_out;

  fused_resd1<<<Bn / 4, 1024, 0, stream>>>(x, Wd, bd, Wt, bt, Wa, ba, Wr, br,
                                           gamma, beta, out);
  (void)in_sizes; (void)n_in; (void)out_size; (void)d_ws; (void)ws_size;
}

// Round 5
// 95.318 us; speedup vs baseline: 1.1277x; 1.1065x over previous
//
#include <hip/hip_runtime.h>
#include <math.h>

// B=1024, D=128, H=128
#define Bn 1024
#define Dn 128
#define Hn 128

// Single fused kernel: 256 blocks x 1024 threads (16 waves/CU, 1 block/CU).
// v6 = v1's phase 1 + B1 byte-identical (every variant that touched code
// before B1 regressed: v4 spilled xi to scratch, v5 perturbed the hot-loop
// codegen). Tail-only restructure:
//  - tau computed by threads [512,768) in the reduce window, reading x/Wt
//    straight from global (L2-resident) -> xs/wt_s staging deleted.
//  - ysc = Wr.x + br computed by threads [768,1024) in the same window.
//  - 4 barriers (v1 had 5); 4a (Wd matvec) and LN are verbatim v1.
__global__ __launch_bounds__(1024) void fused_resd1(
    const float* __restrict__ x,
    const float* __restrict__ Wd, const float* __restrict__ bd,
    const float* __restrict__ Wt, const float* __restrict__ bt,
    const float* __restrict__ Wa, const float* __restrict__ ba,
    const float* __restrict__ Wr, const float* __restrict__ br,
    const float* __restrict__ gamma, const float* __restrict__ beta,
    float* __restrict__ out) {
  const int t = threadIdx.x;
  const int c = t & 31;   // column quad: cols 4c..4c+3
  const int g = t >> 5;   // j-group in [0,32)
  const int i0 = blockIdx.x << 2;

  __shared__ float red[32][4][Dn];  // 64 KB: per-group partial column sums
  __shared__ float dms[4][Dn];
  __shared__ float ms[4][Hn];
  __shared__ float ysc[4][Hn];      // Wr.x + br
  __shared__ float ys[4][Hn];
  __shared__ float tau_s[4];        // 1/tau

  // ---- Phase 1: all-pairs partial sums, 8 loads in flight (verbatim v1) ----
  float4 xi[4];
#pragma unroll
  for (int r = 0; r < 4; ++r)
    xi[r] = *(const float4*)(x + (size_t)(i0 + r) * Dn + c * 4);

  float4 acc[4];
#pragma unroll
  for (int r = 0; r < 4; ++r) acc[r] = make_float4(0.f, 0.f, 0.f, 0.f);

  const float4* xq = (const float4*)x + (size_t)g * 32 * (Dn / 4) + c;
#pragma unroll 1
  for (int jj = 0; jj < 32; jj += 8) {
    float4 xj[8];
#pragma unroll
    for (int u = 0; u < 8; ++u) xj[u] = xq[(size_t)(jj + u) * (Dn / 4)];
#pragma unroll
    for (int u = 0; u < 8; ++u) {
#pragma unroll
      for (int r = 0; r < 4; ++r) {
        acc[r].x += fabsf(xi[r].x - xj[u].x);
        acc[r].y += fabsf(xi[r].y - xj[u].y);
        acc[r].z += fabsf(xi[r].z - xj[u].z);
        acc[r].w += fabsf(xi[r].w - xj[u].w);
      }
    }
  }
#pragma unroll
  for (int r = 0; r < 4; ++r) *(float4*)&red[g][r][c * 4] = acc[r];
  __syncthreads();  // B1

  // ---- Window 1: group-reduce (t<512) || tau [512,768) || Wr.x [768,1024) --
  if (t < 512) {
    const int r = t >> 7, d = t & 127;
    float s = 0.f;
#pragma unroll
    for (int gg = 0; gg < 32; ++gg) s += red[gg][r][d];
    dms[r][d] = s * (1.0f / 1024.0f);
  } else if (t < 768) {
    // tau per row: one wave per row, x and Wt read from global (L2-resident).
    const int tt = t - 512;
    const int r = tt >> 6, p = tt & 63;
    const float* xr = x + (size_t)(i0 + r) * Dn;
    float partial = xr[p] * Wt[p] + xr[p + 64] * Wt[p + 64];
#pragma unroll
    for (int off = 32; off; off >>= 1) partial += __shfl_xor(partial, off, 64);
    if (p == 0) {
      const float z = partial + bt[0];
      const float sp = fmaxf(z, 0.f) + log1pf(expf(-fabsf(z)));  // softplus
      tau_s[r] = 1.0f / (fmaxf(sp, 0.01f) + 1.0f);
    }
  } else {
    // ysc = Wr.x + br, 2 rows per thread, x read from global.
    const int tt = t - 768;
    const int h = tt & 127;
    const int g4 = tt >> 7;
    const int r0 = 2 * g4, r1 = 2 * g4 + 1;
    float c0 = br[h], c1 = c0;
    const float4* wr = (const float4*)(Wr + (size_t)h * Dn);
    const float4* x0 = (const float4*)(x + (size_t)(i0 + r0) * Dn);
    const float4* x1 = (const float4*)(x + (size_t)(i0 + r1) * Dn);
#pragma unroll 4
    for (int k4 = 0; k4 < Dn / 4; ++k4) {
      const float4 rv = wr[k4];
      const float4 a0 = x0[k4];
      const float4 a1 = x1[k4];
      c0 += rv.x * a0.x + rv.y * a0.y + rv.z * a0.z + rv.w * a0.w;
      c1 += rv.x * a1.x + rv.y * a1.y + rv.z * a1.z + rv.w * a1.w;
    }
    ysc[r0][h] = c0;
    ysc[r1][h] = c1;
  }
  __syncthreads();  // B2

  // ---- Phase 4a: ms = (Wd . dm + bd) / tau (t<256, verbatim v1) ----
  if (t < 256) {
    const int h = t & 127;
    const int g4 = t >> 7;
    const int r0 = 2 * g4, r1 = 2 * g4 + 1;
    float m0 = bd[h], m1 = m0;
    const float4* w = (const float4*)(Wd + (size_t)h * Dn);
#pragma unroll 4
    for (int k4 = 0; k4 < Dn / 4; ++k4) {
      const float4 wv = w[k4];
      const int k = k4 * 4;
      m0 += wv.x * dms[r0][k] + wv.y * dms[r0][k + 1] + wv.z * dms[r0][k + 2] +
            wv.w * dms[r0][k + 3];
      m1 += wv.x * dms[r1][k] + wv.y * dms[r1][k + 1] + wv.z * dms[r1][k + 2] +
            wv.w * dms[r1][k + 3];
    }
    ms[r0][h] = m0 * tau_s[r0];
    ms[r1][h] = m1 * tau_s[r1];
  }
  __syncthreads();  // B3

  // ---- Phase 4b: ys = relu(Wa . m + ba) + ysc (t<256) ----
  if (t < 256) {
    const int h = t & 127;
    const int g4 = t >> 7;
    const int r0 = 2 * g4, r1 = 2 * g4 + 1;
    float q0 = ba[h], q1 = q0;
    const float4* wa = (const float4*)(Wa + (size_t)h * Dn);
#pragma unroll 4
    for (int k4 = 0; k4 < Dn / 4; ++k4) {
      const float4 av = wa[k4];
      const int k = k4 * 4;
      q0 += av.x * ms[r0][k] + av.y * ms[r0][k + 1] + av.z * ms[r0][k + 2] +
            av.w * ms[r0][k + 3];
      q1 += av.x * ms[r1][k] + av.y * ms[r1][k + 1] + av.z * ms[r1][k + 2] +
            av.w * ms[r1][k + 3];
    }
    ys[r0][h] = fmaxf(q0, 0.f) + ysc[r0][h];
    ys[r1][h] = fmaxf(q1, 0.f) + ysc[r1][h];
  }
  __syncthreads();  // B4

  // ---- Phase 5: LayerNorm (one wave per row, t<256, verbatim v1) ----
  if (t < 256) {
    const int r = t >> 6, p = t & 63;
    const float v0 = ys[r][p], v1 = ys[r][p + 64];
    float s = v0 + v1;
    float q = v0 * v0 + v1 * v1;
#pragma unroll
    for (int off = 32; off; off >>= 1) {
      s += __shfl_xor(s, off, 64);
      q += __shfl_xor(q, off, 64);
    }
    const float mu = s * (1.0f / 128.0f);
    const float var = q * (1.0f / 128.0f) - mu * mu;
    const float rs = rsqrtf(var + 1e-5f);
    float* o = out + (size_t)(i0 + r) * Hn;
    o[p]      = (v0 - mu) * rs * gamma[p]      + beta[p];
    o[p + 64] = (v1 - mu) * rs * gamma[p + 64] + beta[p + 64];
  }
}

extern "C" void kernel_launch(void* const* d_in, const int* in_sizes, int n_in,
                              void* d_out, int out_size, void* d_ws,
                              size_t ws_size, hipStream_t stream) {
  const float* x     = (const float*)d_in[0];
  const float* Wd    = (const float*)d_in[1];
  const float* bd    = (const float*)d_in[2];
  const float* Wt    = (const float*)d_in[3];
  const float* bt    = (const float*)d_in[4];
  const float* Wa    = (const float*)d_in[5];
  const float* ba    = (const float*)d_in[6];
  const float* Wr    = (const float*)d_in[7];
  const float* br    = (const float*)d_in[8];
  const float* gamma = (const float*)d_in[9];
  const float* beta  = (const float*)d_in[10];
  float* out = (float*)d_out;

  fused_resd1<<<Bn / 4, 1024, 0, stream>>>(x, Wd, bd, Wt, bt, Wa, ba, Wr, br,
                                           gamma, beta, out);
  (void)in_sizes; (void)n_in; (void)out_size; (void)d_ws; (void)ws_size;
}